// Round 1
// baseline (685.327 us; speedup 1.0000x reference)
//
#include <hip/hip_runtime.h>
#include <math.h>

// Problem: factor [65536, 2048] fp32.
//   f = row-L2-normalize(factor)  (torch F.normalize, eps=1e-12)
//   adj[i] = <f_i, f_{i+1}>, out = -WEIGHT * 2 * mean(adj)   (single fp32 scalar)
//
// Strategy: single streaming pass computes per-row sum-of-squares and
// consecutive-row dot products (each element read ~once); tiny second pass
// does the normalized sum in fp64.

#define N_ROWS 65536
#define N_COLS 2048
#define ROWS_PER_WAVE 16   // 6.25% boundary re-read; 4096 waves = 16 waves/CU

__global__ __launch_bounds__(256) void tcr_pass1(const float* __restrict__ x,
                                                 float* __restrict__ sq,
                                                 float* __restrict__ cross) {
    const int wid  = (blockIdx.x * 256 + threadIdx.x) >> 6;   // global wave id
    const int lane = threadIdx.x & 63;
    const long r0 = (long)wid * ROWS_PER_WAVE;

    const float4* rowp = (const float4*)x;   // row r = float4 indices [r*512, r*512+512)

    // Load first row of chunk; lane covers float4 indices lane + k*64, k=0..7 (coalesced).
    float4 prev[8];
    {
        long base = r0 * 512 + lane;
        #pragma unroll
        for (int k = 0; k < 8; ++k) prev[k] = rowp[base + (long)k * 64];
    }
    // sq of first row
    {
        float s = 0.f;
        #pragma unroll
        for (int k = 0; k < 8; ++k)
            s += prev[k].x * prev[k].x + prev[k].y * prev[k].y +
                 prev[k].z * prev[k].z + prev[k].w * prev[k].w;
        #pragma unroll
        for (int off = 32; off; off >>= 1) s += __shfl_xor(s, off, 64);
        if (lane == 0) sq[r0] = s;
    }

    const int rend = (int)r0 + ROWS_PER_WAVE;   // last row index we touch (belongs to next chunk)
    for (int r = (int)r0 + 1; r <= rend; ++r) {
        if (r >= N_ROWS) break;
        float4 cur[8];
        long base = (long)r * 512 + lane;
        #pragma unroll
        for (int k = 0; k < 8; ++k) cur[k] = rowp[base + (long)k * 64];

        float sqp = 0.f, crp = 0.f;
        #pragma unroll
        for (int k = 0; k < 8; ++k) {
            sqp += cur[k].x * cur[k].x + cur[k].y * cur[k].y +
                   cur[k].z * cur[k].z + cur[k].w * cur[k].w;
            crp += prev[k].x * cur[k].x + prev[k].y * cur[k].y +
                   prev[k].z * cur[k].z + prev[k].w * cur[k].w;
            prev[k] = cur[k];
        }
        #pragma unroll
        for (int off = 32; off; off >>= 1) {
            sqp += __shfl_xor(sqp, off, 64);
            crp += __shfl_xor(crp, off, 64);
        }
        if (lane == 0) {
            cross[r - 1] = crp;            // pair (r-1, r)
            if (r < rend) sq[r] = sqp;     // row r's sq belongs to this chunk only if r < rend
        }
    }
}

// Final reduction: sum cross[i] / (max(sqrt(sq[i]),eps) * max(sqrt(sq[i+1]),eps)),
// scale, atomic-accumulate into the fp32 scalar output. fp64 accumulation: the
// sum has heavy cancellation (65535 terms ~±0.02 netting ~0.4).
__global__ __launch_bounds__(256) void tcr_pass2(const float* __restrict__ sq,
                                                 const float* __restrict__ cross,
                                                 float* __restrict__ out) {
    const int tid    = blockIdx.x * 256 + threadIdx.x;
    const int stride = gridDim.x * 256;
    double acc = 0.0;
    for (int i = tid; i < N_ROWS - 1; i += stride) {
        double ni = fmax(sqrt((double)sq[i]),     1e-12);
        double nj = fmax(sqrt((double)sq[i + 1]), 1e-12);
        acc += (double)cross[i] / (ni * nj);
    }
    __shared__ double sd[256];
    sd[threadIdx.x] = acc;
    __syncthreads();
    for (int s = 128; s; s >>= 1) {
        if (threadIdx.x < s) sd[threadIdx.x] += sd[threadIdx.x + s];
        __syncthreads();
    }
    if (threadIdx.x == 0) {
        // out = -WEIGHT * (p1 + p2) = -0.01 * 2 * sum/(N-1)
        double partial = sd[0] * (-2.0 * 0.01 / (double)(N_ROWS - 1));
        atomicAdd(out, (float)partial);
    }
}

extern "C" void kernel_launch(void* const* d_in, const int* in_sizes, int n_in,
                              void* d_out, int out_size, void* d_ws, size_t ws_size,
                              hipStream_t stream) {
    const float* factor = (const float*)d_in[0];
    float* out = (float*)d_out;

    // Workspace layout: sq[N_ROWS] floats, then cross[N_ROWS] floats (cross[N-1] unused).
    float* sq    = (float*)d_ws;
    float* cross = sq + N_ROWS;

    // Pass 1: 65536 rows / 16 rows-per-wave = 4096 waves = 1024 blocks of 4 waves.
    const int n_waves  = N_ROWS / ROWS_PER_WAVE;
    const int n_blocks = n_waves / 4;
    tcr_pass1<<<n_blocks, 256, 0, stream>>>(factor, sq, cross);

    // Zero the output scalar (harness poisons it to 0xAA before every timed call).
    hipMemsetAsync(d_out, 0, sizeof(float), stream);

    // Pass 2: tiny reduction over 65535 pairs.
    tcr_pass2<<<64, 256, 0, stream>>>(sq, cross, out);
}